// Round 12
// baseline (244.134 us; speedup 1.0000x reference)
//
#include <hip/hip_runtime.h>

#define NB 4
#define NS 2048
#define ND 1024
#define NH 16
#define NHD 64
#define NTOK (NB*NS)

typedef float f32x4 __attribute__((ext_vector_type(4)));
typedef __bf16 bf16x8 __attribute__((ext_vector_type(8)));
typedef __bf16 bf16x4 __attribute__((ext_vector_type(4)));

#define MFMA16(a,b,c) __builtin_amdgcn_mfma_f32_16x16x32_bf16((a),(b),(c),0,0,0)
#define SBAR() __builtin_amdgcn_s_barrier()
#define VMCNT(n) asm volatile("s_waitcnt vmcnt(" #n ")" ::: "memory")
#define LGKM(n) asm volatile("s_waitcnt lgkmcnt(" #n ")" ::: "memory")
#define SCHEDB() __builtin_amdgcn_sched_barrier(0)

__device__ __forceinline__ float fexp2(float x) {
#if __has_builtin(__builtin_amdgcn_exp2f)
  return __builtin_amdgcn_exp2f(x);
#else
  return __expf(x * 0.69314718056f);
#endif
}

__device__ __forceinline__ void gload_lds16(const __bf16* g, const __bf16* l) {
  __builtin_amdgcn_global_load_lds(
      (const __attribute__((address_space(1))) void*)(uintptr_t)(const void*)g,
      (__attribute__((address_space(3))) void*)(uint32_t)(uintptr_t)(const void*)l,
      16, 0, 0);
}

// ---------------- fused prep: W transpose (blocks 0..1023) + x convert (rest) ----------------
__global__ void k_prep(const float* __restrict__ x,
                       const float* __restrict__ w0, const float* __restrict__ w1,
                       const float* __restrict__ w2, const float* __restrict__ w3,
                       __bf16* __restrict__ xb, __bf16* __restrict__ wqkvt,
                       __bf16* __restrict__ wot) {
  __shared__ float tl[64][65];
  const int bi = blockIdx.x;
  if (bi < 1024) {
    const int z = bi >> 8, rem = bi & 255;
    const float* src = (z==0)?w0:(z==1)?w1:(z==2)?w2:w3;
    __bf16* dst = (z<3) ? (wqkvt + (size_t)z*ND*ND) : wot;
    const int kb = (rem>>4)*64, nb = (rem&15)*64;
    const int c = threadIdx.x & 63, r0 = threadIdx.x >> 6;
    for (int i=0;i<16;i++) { int r = r0*16+i; tl[r][c] = src[(size_t)(kb+r)*ND + nb + c]; }
    __syncthreads();
    for (int i=0;i<16;i++) { int r = r0*16+i; dst[(size_t)(nb+r)*ND + kb + c] = (__bf16)tl[c][r]; }
  } else {
    const int i = (bi - 1024)*256 + threadIdx.x;
    float4 v = ((const float4*)x)[i];
    bf16x4 o = { (__bf16)v.x, (__bf16)v.y, (__bf16)v.z, (__bf16)v.w };
    ((bf16x4*)xb)[i] = o;
  }
}

// ---------------- fused QKV GEMM: 256x128 tile, BK=32, 4 waves (2Mx2N), ----------------
// per-wave 128x64 out, 3-buffer depth-2, 2 blocks/CU. (frozen from R11)
__global__ __launch_bounds__(256, 2) void k_gemm_qkv(
    const __bf16* __restrict__ A, const __bf16* __restrict__ Bt,
    __bf16* __restrict__ qs, __bf16* __restrict__ ks, __bf16* __restrict__ vt) {
  constexpr int BUFE = (256+128)*32;                 // 12288 elems = 24 KiB
  __shared__ __align__(16) __bf16 lds[3*BUFE];       // 72 KiB -> 2 blocks/CU
  const int tid = threadIdx.x;
  const int wid = tid>>6, lane = tid&63;             // wid 0..3
  const int wr = wid>>1, wc = wid&1;
  const int lrow = lane&15, lg = lane>>4;
  const int srow4 = lane>>2;                          // row within 16-row chunk
  const int scol  = ((lane&3) ^ ((lane>>3)&3))*8;     // pre-swizzled global col

  const int id  = blockIdx.x;                        // 768 blocks
  const int xcd = id & 7;
  const int nl  = id >> 3;
  const int st  = nl >> 5;                           // supertile 0..2
  const int u   = nl & 31;
  const int bx  = xcd*4 + (u >> 3);                  // 0..31
  const int by  = st*8 + (u & 7);                    // 0..23
  const int m0 = bx*256, n0 = by*128;

  auto stage = [&](int t, int bsel) {
    __bf16* buf = lds + bsel*BUFE;
    const int k0 = t*32;
    #pragma unroll
    for (int i=0;i<4;i++) {
      int c = wid + i*4;                             // A chunks 0..15 (16 rows each)
      gload_lds16(A + (size_t)(m0 + c*16 + srow4)*ND + k0 + scol, buf + c*512);
    }
    #pragma unroll
    for (int i=0;i<2;i++) {
      int c = wid + i*4;                             // B chunks 0..7
      gload_lds16(Bt + (size_t)(n0 + c*16 + srow4)*ND + k0 + scol, buf + 8192 + c*512);
    }
  };

  const int slot = (lg ^ ((lrow>>1)&3)) << 4;        // read-side swizzle (bytes)
  const int abase = (wr*128 + lrow)*64 + slot;
  const int bbase = 16384 + (wc*64 + lrow)*64 + slot;

  f32x4 acc[8][4];
  f32x4 zero = {0.f,0.f,0.f,0.f};
  #pragma unroll
  for (int i=0;i<8;i++) for (int j=0;j<4;j++) acc[i][j] = zero;

  stage(0,0);
  stage(1,1);
  for (int t=0; t<32; ++t) {
    if (t < 30) stage(t+2, (t+2)%3);
    if (t < 30)      { VMCNT(12); }   // tiles t+1,t+2 in flight; t landed
    else if (t == 30){ VMCNT(6);  }
    else             { VMCNT(0);  }
    SBAR();
    const char* L = (const char*)(lds + (t%3)*BUFE);
    bf16x8 bfr[4], af[8];
    #pragma unroll
    for (int cb=0;cb<4;cb++) bfr[cb] = *(const bf16x8*)(L + bbase + cb*1024);
    #pragma unroll
    for (int mf=0;mf<4;mf++) af[mf] = *(const bf16x8*)(L + abase + mf*1024);
    SCHEDB();                                        // first 8 reads issue before...
    #pragma unroll
    for (int mf=4;mf<8;mf++) af[mf] = *(const bf16x8*)(L + abase + mf*1024);
    LGKM(4);                                         // ...these 4; wait first 8
    SCHEDB();
    __builtin_amdgcn_s_setprio(1);
    #pragma unroll
    for (int mf=0;mf<4;mf++)
      #pragma unroll
      for (int cb=0;cb<4;cb++)
        acc[mf][cb] = MFMA16(af[mf], bfr[cb], acc[mf][cb]);
    __builtin_amdgcn_s_setprio(0);
    LGKM(0);
    SCHEDB();
    __builtin_amdgcn_s_setprio(1);
    #pragma unroll
    for (int mf=4;mf<8;mf++)
      #pragma unroll
      for (int cb=0;cb<4;cb++)
        acc[mf][cb] = MFMA16(af[mf], bfr[cb], acc[mf][cb]);
    __builtin_amdgcn_s_setprio(0);
    SBAR();
  }

  // ---- coalesced epilogue via LDS restage (per-wave 128x64) ----
  const int which = by >> 3;                  // 0:q 1:k 2:v (block-uniform)
  const int h = (by&7)*2 + wc;                // wave-uniform head
  __bf16* ws = lds + wid*8192;                // 16 KiB per wave
  const int tokbase = m0 + wr*128;
  const int b = tokbase >> 11, s0 = tokbase & 2047;

  if (which < 2) {
    __bf16* dst = which ? ks : qs;
    #pragma unroll
    for (int mf=0;mf<8;mf++)
      #pragma unroll
      for (int cb=0;cb<4;cb++)
        #pragma unroll
        for (int r=0;r<4;r++) {
          int row = mf*16 + lg*4 + r;         // 0..127
          int chunk = (cb*2 + (lrow>>3)) ^ (row&7);
          *(__bf16*)((char*)ws + row*128 + chunk*16 + (lrow&7)*2) = (__bf16)acc[mf][cb][r];
        }
    #pragma unroll
    for (int p=0;p<16;p++) {
      int row = p*8 + (lane>>3);
      int chunk = (lane&7) ^ (row&7);
      bf16x8 v = *(const bf16x8*)((char*)ws + row*128 + chunk*16);
      *(bf16x8*)(dst + ((size_t)(b*NH + h)*NS + s0 + row)*NHD + (lane&7)*8) = v;
    }
  } else {
    // transposed restage: ws[hd][s] rows of 256 B (16 slots), slot ^= hd&15
    #pragma unroll
    for (int mf=0;mf<8;mf++)
      #pragma unroll
      for (int cb=0;cb<4;cb++) {
        bf16x4 pk = { (__bf16)acc[mf][cb][0], (__bf16)acc[mf][cb][1],
                      (__bf16)acc[mf][cb][2], (__bf16)acc[mf][cb][3] };
        int hd = cb*16 + lrow;
        int slotv = (mf*2 + (lg>>1)) ^ (hd&15);
        *(bf16x4*)((char*)ws + hd*256 + slotv*16 + (lg&1)*8) = pk;
      }
    #pragma unroll
    for (int p=0;p<16;p++) {
      int idx = p*64 + lane;
      int hd = idx>>4, c = idx&15;
      bf16x8 v = *(const bf16x8*)((char*)ws + hd*256 + ((c ^ (hd&15)))*16);
      *(bf16x8*)(vt + ((size_t)(b*NH + h)*NHD + hd)*NS + s0 + c*8) = v;
    }
  }
}

// ---------------- output projection GEMM: 256x128, BK=64, 3-buffer depth-2 (frozen) ----------------
__global__ __launch_bounds__(512, 2) void k_gemm_out(
    const __bf16* __restrict__ A, const __bf16* __restrict__ Bt,
    const float* __restrict__ bo, float* __restrict__ out) {
  constexpr int BUFE = (256+128)*64;
  __shared__ __align__(16) __bf16 lds[3*BUFE];       // 144 KiB
  const int tid = threadIdx.x;
  const int wid = tid>>6, lane = tid&63;
  const int wr = wid>>1, wc = wid&1;
  const int lrow = lane&15, lg = lane>>4;
  const int srow = lane>>3;
  const int scol = ((lane&7) ^ srow)*8;

  const int id  = blockIdx.x;                        // 256 blocks
  const int xcd = id & 7;
  const int nl  = id >> 3;                           // 0..31
  const int bx  = xcd*4 + (nl >> 3);                 // 0..31
  const int by  = nl & 7;                            // 0..7
  const int m0 = bx*256, n0 = by*128;

  auto stage = [&](int t, int bsel) {
    __bf16* buf = lds + bsel*BUFE;
    const int k0 = t*64;
    #pragma unroll
    for (int i=0;i<4;i++) {
      int c = wid + i*8;
      gload_lds16(A + (size_t)(m0 + c*8 + srow)*ND + k0 + scol, buf + c*512);
    }
    #pragma unroll
    for (int i=0;i<2;i++) {
      int c = wid + i*8;
      gload_lds16(Bt + (size_t)(n0 + c*8 + srow)*ND + k0 + scol, buf + 16384 + c*512);
    }
  };

  int kx[8];
  #pragma unroll
  for (int kk=0;kk<8;kk++) kx[kk] = ((kk ^ (lrow&7)) << 4);
  const int abase = (wr*64 + lrow)*128;
  const int bbase = 32768 + (wc*64 + lrow)*128;

  f32x4 acc[4][4];
  f32x4 zero = {0.f,0.f,0.f,0.f};
  #pragma unroll
  for (int i=0;i<4;i++) for (int j=0;j<4;j++) acc[i][j] = zero;

  stage(0,0);
  stage(1,1);
  for (int t=0; t<16; ++t) {
    if (t < 14) stage(t+2, (t+2)%3);
    if (t < 14)      { VMCNT(12); }
    else if (t == 14){ VMCNT(6);  }
    else             { VMCNT(0);  }
    SBAR();
    const char* L = (const char*)(lds + (t%3)*BUFE);
    bf16x8 bfr[4][2], af[4][2];
    #pragma unroll
    for (int cb=0;cb<4;cb++)
      #pragma unroll
      for (int ksi=0;ksi<2;ksi++)
        bfr[cb][ksi] = *(const bf16x8*)(L + bbase + cb*2048 + kx[ksi*4+lg]);
    #pragma unroll
    for (int mf=0;mf<2;mf++)
      #pragma unroll
      for (int ksi=0;ksi<2;ksi++)
        af[mf][ksi] = *(const bf16x8*)(L + abase + mf*2048 + kx[ksi*4+lg]);
    SCHEDB();
    #pragma unroll
    for (int mf=2;mf<4;mf++)
      #pragma unroll
      for (int ksi=0;ksi<2;ksi++)
        af[mf][ksi] = *(const bf16x8*)(L + abase + mf*2048 + kx[ksi*4+lg]);
    LGKM(4);
    SCHEDB();
    __builtin_amdgcn_s_setprio(1);
    #pragma unroll
    for (int mf=0;mf<2;mf++)
      #pragma unroll
      for (int cb=0;cb<4;cb++)
        #pragma unroll
        for (int ksi=0;ksi<2;ksi++)
          acc[mf][cb] = MFMA16(af[mf][ksi], bfr[cb][ksi], acc[mf][cb]);
    __builtin_amdgcn_s_setprio(0);
    LGKM(0);
    SCHEDB();
    __builtin_amdgcn_s_setprio(1);
    #pragma unroll
    for (int mf=2;mf<4;mf++)
      #pragma unroll
      for (int cb=0;cb<4;cb++)
        #pragma unroll
        for (int ksi=0;ksi<2;ksi++)
          acc[mf][cb] = MFMA16(af[mf][ksi], bfr[cb][ksi], acc[mf][cb]);
    __builtin_amdgcn_s_setprio(0);
    SBAR();
  }

  // epilogue: bias + f32 store (256B segments per 16-lane group, no RMW)
  #pragma unroll
  for (int cb=0;cb<4;cb++) {
    const int n = n0 + wc*64 + cb*16 + lrow;
    const float bias = bo[n];
    #pragma unroll
    for (int mf=0;mf<4;mf++)
      #pragma unroll
      for (int r=0;r<4;r++) {
        const int m = m0 + wr*64 + mf*16 + lg*4 + r;
        out[(size_t)m*ND + n] = acc[mf][cb][r] + bias;
      }
  }
}

// ---------------- flash attention: swapped-QK^T, V from global (no sV), 4 blk/CU ----------------
// q/k [B*H][S][HD] bf16, vt [B*H][HD][S] bf16 -> ctx [B][S][H][HD] bf16
__global__ __launch_bounds__(256, 4) void k_attn(
    const __bf16* __restrict__ qs, const __bf16* __restrict__ ks,
    const __bf16* __restrict__ vt, __bf16* __restrict__ ctx) {
  __shared__ __align__(16) __bf16 sK[2][64*64];
  __shared__ __align__(16) __bf16 sP[4][32*72];   // [q][kv], stride 72 (144B = 36 banks)
  const int tid = threadIdx.x, w = tid >> 6, lane = tid & 63;
  const int lrow = lane & 15, lg = lane >> 4;
  const int bh = blockIdx.x;
  const int bq = 15 - blockIdx.y;
  const int nt = 2*bq + 2;
  const size_t base = (size_t)bh * NS * NHD;
  const __bf16* Kg = ks + base;
  const __bf16* Vg = vt + base;   // [hd][s]
  __bf16* sPw = sP[w];

  const int q0w = bq*128 + w*32;
  // Q prescaled by (1/sqrt(HD))*log2(e) so P = exp2(S)
  bf16x8 qf[2][2];
  for (int rb=0;rb<2;rb++)
    for (int kk=0;kk<2;kk++) {
      bf16x8 v = *(const bf16x8*)(qs + base + (size_t)(q0w + rb*16 + lrow)*NHD + kk*32 + lg*8);
      bf16x8 o;
      for (int j=0;j<8;j++) o[j] = (__bf16)((float)v[j] * 0.1803368801f);
      qf[rb][kk] = o;
    }

  int koffB[4][2];
  for (int cb=0;cb<4;cb++) {
    int r = cb*16 + lrow;
    for (int kk=0;kk<2;kk++)
      koffB[cb][kk] = r*128 + (((kk*4 + lg) ^ (r & 7)) << 4);
  }
  // per-lane V fragment base pointers: V^T[hd=cb*16+lrow][kv = kk*32+lg*8], advance +64/tile
  const __bf16* vb8[2][4];
  for (int kk=0;kk<2;kk++)
    for (int cb=0;cb<4;cb++)
      vb8[kk][cb] = Vg + (size_t)(cb*16 + lrow)*NS + kk*32 + lg*8;

  const int s_r[2]  = { (w + 0)*8 + (lane>>3), (w + 4)*8 + (lane>>3) };
  const int s_u[2]  = { (lane&7) ^ (s_r[0]&7), (lane&7) ^ (s_r[1]&7) };

  f32x4 zero = {0.f,0.f,0.f,0.f};
  f32x4 oacc[2][4];
  float psum[2] = {0.f, 0.f};
  for (int rb=0;rb<2;rb++) for(int cb=0;cb<4;cb++) oacc[rb][cb]=zero;

  for (int i=0;i<2;i++)
    gload_lds16(Kg + (size_t)s_r[i]*NHD + s_u[i]*8, sK[0] + (w + i*4)*512);
  asm volatile("s_waitcnt vmcnt(0)" ::: "memory");
  __syncthreads();

  int buf = 0;
  for (int t = 0; t < nt; ++t) {
    const bool compute = !(t == nt-1 && w < 2);   // waves 0,1: last tile fully masked
    // V loads FIRST (in-order vmcnt: V-ready at <=2 outstanding, K stays in flight)
    bf16x8 vf[2][4];
    if (compute) {
      #pragma unroll
      for (int kk=0;kk<2;kk++)
        #pragma unroll
        for (int cb=0;cb<4;cb++)
          vf[kk][cb] = *(const bf16x8*)(vb8[kk][cb] + t*64);
    }
    // K prefetch for t+1
    if (t+1 < nt) {
      const __bf16* Kt = Kg + (size_t)(t+1)*64*NHD;
      for (int i=0;i<2;i++)
        gload_lds16(Kt + (size_t)s_r[i]*NHD + s_u[i]*8, sK[buf^1] + (w + i*4)*512);
    }
    if (compute) {
      const __bf16* bK = sK[buf];
      const bool bdry = (t >= nt-2);
      // S^T = K Q^T: lane owns rows kv=cb*16+lg*4+r, col q=rb*16+lrow
      for (int cb=0;cb<4;cb++) {
        bf16x8 kf0 = *(const bf16x8*)((const char*)bK + koffB[cb][0]);
        bf16x8 kf1 = *(const bf16x8*)((const char*)bK + koffB[cb][1]);
        const int kvb = t*64 + cb*16 + lg*4;
        for (int rb=0;rb<2;rb++) {
          f32x4 s4 = MFMA16(kf0, qf[rb][0], zero);
          s4 = MFMA16(kf1, qf[rb][1], s4);
          const int qg = q0w + rb*16 + lrow;
          float e0 = fexp2(s4[0]), e1 = fexp2(s4[1]);
          float e2 = fexp2(s4[2]), e3 = fexp2(s4[3]);
          if (bdry) {
            if (kvb + 0 > qg) e0 = 0.f;
            if (kvb + 1 > qg) e1 = 0.f;
            if (kvb + 2 > qg) e2 = 0.f;
            if (kvb + 3 > qg) e3 = 0.f;
          }
          psum[rb] += (e0 + e1) + (e2 + e3);
          bf16x4 pk = { (__bf16)e0, (__bf16)e1, (__bf16)e2, (__bf16)e3 };
          *(bf16x4*)(sPw + (rb*16 + lrow)*72 + cb*16 + lg*4) = pk;  // ds_write_b64
        }
      }
      // O += P V from registers
      for (int kk=0;kk<2;kk++) {
        bf16x8 pa0 = *(const bf16x8*)(sPw + (lrow)*72      + kk*32 + lg*8);
        bf16x8 pa1 = *(const bf16x8*)(sPw + (16 + lrow)*72 + kk*32 + lg*8);
        for (int cb=0;cb<4;cb++) {
          oacc[0][cb] = MFMA16(pa0, vf[kk][cb], oacc[0][cb]);
          oacc[1][cb] = MFMA16(pa1, vf[kk][cb], oacc[1][cb]);
        }
      }
    }
    asm volatile("s_waitcnt vmcnt(0)" ::: "memory");   // drain K prefetch
    __syncthreads();
    buf ^= 1;
  }

  // psum[rb]: partial row-sum for q=rb*16+lrow over this lane's kv subset
  float inv[2];
  for (int rb=0;rb<2;rb++) {
    float s = psum[rb];
    s += __shfl_xor(s, 16);
    s += __shfl_xor(s, 32);
    inv[rb] = 1.0f / s;
  }

  // ---- coalesced ctx write via LDS restage (reuse sK; all waves synced) ----
  __bf16* ws = &sK[0][0] + w*2048;            // 32 rows x 64 cols per wave
  const int b = bh >> 4, h = bh & 15;
  for (int rb=0;rb<2;rb++)
    for (int cb=0;cb<4;cb++)
      for (int r=0;r<4;r++) {
        int row = rb*16 + lg*4 + r;
        float nrm = __shfl(inv[rb], lg*4 + r);
        int chunk = (cb*2 + (lrow>>3)) ^ (row&7);
        *(__bf16*)((char*)ws + row*128 + chunk*16 + (lrow&7)*2) =
            (__bf16)(oacc[rb][cb][r] * nrm);
      }
  for (int p=0;p<4;p++) {
    int row = p*8 + (lane>>3);
    int chunk = (lane&7) ^ (row&7);
    bf16x8 v = *(const bf16x8*)((char*)ws + row*128 + chunk*16);
    int q = q0w + row;
    *(bf16x8*)(ctx + ((size_t)(b*NS + q))*ND + h*NHD + (lane&7)*8) = v;
  }
}

extern "C" void kernel_launch(void* const* d_in, const int* in_sizes, int n_in,
                              void* d_out, int out_size, void* d_ws, size_t ws_size,
                              hipStream_t stream) {
  const float* x  = (const float*)d_in[0];
  const float* Wq = (const float*)d_in[1];
  const float* Wk = (const float*)d_in[2];
  const float* Wv = (const float*)d_in[3];
  const float* Wo = (const float*)d_in[4];
  const float* bo = (const float*)d_in[5];
  float* out = (float*)d_out;

  __bf16* xb    = (__bf16*)d_ws;
  __bf16* wqkvt = xb    + (size_t)NTOK*ND;
  __bf16* wot   = wqkvt + (size_t)3*ND*ND;
  __bf16* qsc   = wot   + (size_t)ND*ND;
  __bf16* ksc   = qsc   + (size_t)NTOK*ND;
  __bf16* vtc   = ksc   + (size_t)NTOK*ND;
  __bf16* ctx   = vtc   + (size_t)NTOK*ND;

  k_prep<<<1024 + NTOK*ND/(4*256), 256, 0, stream>>>(x, Wq, Wk, Wv, Wo, xb, wqkvt, wot);
  k_gemm_qkv<<<768, 256, 0, stream>>>(xb, wqkvt, qsc, ksc, vtc);
  k_attn<<<dim3(NB*NH, NS/128), 256, 0, stream>>>(qsc, ksc, vtc, ctx);
  k_gemm_out<<<256, 512, 0, stream>>>(ctx, wot, bo, out);
}

// Round 13
// 143.183 us; speedup vs baseline: 1.7050x; 1.7050x over previous
//
#include <hip/hip_runtime.h>

#define NB 4
#define NS 2048
#define ND 1024
#define NH 16
#define NHD 64
#define NTOK (NB*NS)

typedef float f32x4 __attribute__((ext_vector_type(4)));
typedef __bf16 bf16x8 __attribute__((ext_vector_type(8)));
typedef __bf16 bf16x4 __attribute__((ext_vector_type(4)));

#define MFMA16(a,b,c) __builtin_amdgcn_mfma_f32_16x16x32_bf16((a),(b),(c),0,0,0)
#define SBAR() __builtin_amdgcn_s_barrier()
#define VMCNT(n) asm volatile("s_waitcnt vmcnt(" #n ")" ::: "memory")
#define LGKM(n) asm volatile("s_waitcnt lgkmcnt(" #n ")" ::: "memory")
#define SCHEDB() __builtin_amdgcn_sched_barrier(0)

__device__ __forceinline__ float fexp2(float x) {
#if __has_builtin(__builtin_amdgcn_exp2f)
  return __builtin_amdgcn_exp2f(x);
#else
  return __expf(x * 0.69314718056f);
#endif
}

__device__ __forceinline__ void gload_lds16(const __bf16* g, const __bf16* l) {
  __builtin_amdgcn_global_load_lds(
      (const __attribute__((address_space(1))) void*)(uintptr_t)(const void*)g,
      (__attribute__((address_space(3))) void*)(uint32_t)(uintptr_t)(const void*)l,
      16, 0, 0);
}

// ---------------- fused prep: W transpose (blocks 0..1023) + x convert (rest) ----------------
__global__ void k_prep(const float* __restrict__ x,
                       const float* __restrict__ w0, const float* __restrict__ w1,
                       const float* __restrict__ w2, const float* __restrict__ w3,
                       __bf16* __restrict__ xb, __bf16* __restrict__ wqkvt,
                       __bf16* __restrict__ wot) {
  __shared__ float tl[64][65];
  const int bi = blockIdx.x;
  if (bi < 1024) {
    const int z = bi >> 8, rem = bi & 255;
    const float* src = (z==0)?w0:(z==1)?w1:(z==2)?w2:w3;
    __bf16* dst = (z<3) ? (wqkvt + (size_t)z*ND*ND) : wot;
    const int kb = (rem>>4)*64, nb = (rem&15)*64;
    const int c = threadIdx.x & 63, r0 = threadIdx.x >> 6;
    for (int i=0;i<16;i++) { int r = r0*16+i; tl[r][c] = src[(size_t)(kb+r)*ND + nb + c]; }
    __syncthreads();
    for (int i=0;i<16;i++) { int r = r0*16+i; dst[(size_t)(nb+r)*ND + kb + c] = (__bf16)tl[c][r]; }
  } else {
    const int i = (bi - 1024)*256 + threadIdx.x;
    float4 v = ((const float4*)x)[i];
    bf16x4 o = { (__bf16)v.x, (__bf16)v.y, (__bf16)v.z, (__bf16)v.w };
    ((bf16x4*)xb)[i] = o;
  }
}

// ---------------- fused QKV GEMM: 256x128 tile, BK=32, 4 waves (2Mx2N), ----------------
// per-wave 128x64 out, 3-buffer depth-2, 2 blocks/CU. (frozen)
__global__ __launch_bounds__(256, 2) void k_gemm_qkv(
    const __bf16* __restrict__ A, const __bf16* __restrict__ Bt,
    __bf16* __restrict__ qs, __bf16* __restrict__ ks, __bf16* __restrict__ vt) {
  constexpr int BUFE = (256+128)*32;                 // 12288 elems = 24 KiB
  __shared__ __align__(16) __bf16 lds[3*BUFE];       // 72 KiB -> 2 blocks/CU
  const int tid = threadIdx.x;
  const int wid = tid>>6, lane = tid&63;             // wid 0..3
  const int wr = wid>>1, wc = wid&1;
  const int lrow = lane&15, lg = lane>>4;
  const int srow4 = lane>>2;                          // row within 16-row chunk
  const int scol  = ((lane&3) ^ ((lane>>3)&3))*8;     // pre-swizzled global col

  const int id  = blockIdx.x;                        // 768 blocks
  const int xcd = id & 7;
  const int nl  = id >> 3;
  const int st  = nl >> 5;                           // supertile 0..2
  const int u   = nl & 31;
  const int bx  = xcd*4 + (u >> 3);                  // 0..31
  const int by  = st*8 + (u & 7);                    // 0..23
  const int m0 = bx*256, n0 = by*128;

  auto stage = [&](int t, int bsel) {
    __bf16* buf = lds + bsel*BUFE;
    const int k0 = t*32;
    #pragma unroll
    for (int i=0;i<4;i++) {
      int c = wid + i*4;                             // A chunks 0..15 (16 rows each)
      gload_lds16(A + (size_t)(m0 + c*16 + srow4)*ND + k0 + scol, buf + c*512);
    }
    #pragma unroll
    for (int i=0;i<2;i++) {
      int c = wid + i*4;                             // B chunks 0..7
      gload_lds16(Bt + (size_t)(n0 + c*16 + srow4)*ND + k0 + scol, buf + 8192 + c*512);
    }
  };

  const int slot = (lg ^ ((lrow>>1)&3)) << 4;        // read-side swizzle (bytes)
  const int abase = (wr*128 + lrow)*64 + slot;
  const int bbase = 16384 + (wc*64 + lrow)*64 + slot;

  f32x4 acc[8][4];
  f32x4 zero = {0.f,0.f,0.f,0.f};
  #pragma unroll
  for (int i=0;i<8;i++) for (int j=0;j<4;j++) acc[i][j] = zero;

  stage(0,0);
  stage(1,1);
  for (int t=0; t<32; ++t) {
    if (t < 30) stage(t+2, (t+2)%3);
    if (t < 30)      { VMCNT(12); }   // tiles t+1,t+2 in flight; t landed
    else if (t == 30){ VMCNT(6);  }
    else             { VMCNT(0);  }
    SBAR();
    const char* L = (const char*)(lds + (t%3)*BUFE);
    bf16x8 bfr[4], af[8];
    #pragma unroll
    for (int cb=0;cb<4;cb++) bfr[cb] = *(const bf16x8*)(L + bbase + cb*1024);
    #pragma unroll
    for (int mf=0;mf<4;mf++) af[mf] = *(const bf16x8*)(L + abase + mf*1024);
    SCHEDB();                                        // first 8 reads issue before...
    #pragma unroll
    for (int mf=4;mf<8;mf++) af[mf] = *(const bf16x8*)(L + abase + mf*1024);
    LGKM(4);                                         // ...these 4; wait first 8
    SCHEDB();
    __builtin_amdgcn_s_setprio(1);
    #pragma unroll
    for (int mf=0;mf<4;mf++)
      #pragma unroll
      for (int cb=0;cb<4;cb++)
        acc[mf][cb] = MFMA16(af[mf], bfr[cb], acc[mf][cb]);
    __builtin_amdgcn_s_setprio(0);
    LGKM(0);
    SCHEDB();
    __builtin_amdgcn_s_setprio(1);
    #pragma unroll
    for (int mf=4;mf<8;mf++)
      #pragma unroll
      for (int cb=0;cb<4;cb++)
        acc[mf][cb] = MFMA16(af[mf], bfr[cb], acc[mf][cb]);
    __builtin_amdgcn_s_setprio(0);
    SBAR();
  }

  // ---- coalesced epilogue via LDS restage (per-wave 128x64) ----
  const int which = by >> 3;                  // 0:q 1:k 2:v (block-uniform)
  const int h = (by&7)*2 + wc;                // wave-uniform head
  __bf16* ws = lds + wid*8192;                // 16 KiB per wave
  const int tokbase = m0 + wr*128;
  const int b = tokbase >> 11, s0 = tokbase & 2047;

  if (which < 2) {
    __bf16* dst = which ? ks : qs;
    #pragma unroll
    for (int mf=0;mf<8;mf++)
      #pragma unroll
      for (int cb=0;cb<4;cb++)
        #pragma unroll
        for (int r=0;r<4;r++) {
          int row = mf*16 + lg*4 + r;         // 0..127
          int chunk = (cb*2 + (lrow>>3)) ^ (row&7);
          *(__bf16*)((char*)ws + row*128 + chunk*16 + (lrow&7)*2) = (__bf16)acc[mf][cb][r];
        }
    #pragma unroll
    for (int p=0;p<16;p++) {
      int row = p*8 + (lane>>3);
      int chunk = (lane&7) ^ (row&7);
      bf16x8 v = *(const bf16x8*)((char*)ws + row*128 + chunk*16);
      *(bf16x8*)(dst + ((size_t)(b*NH + h)*NS + s0 + row)*NHD + (lane&7)*8) = v;
    }
  } else {
    // transposed restage: ws[hd][s] rows of 256 B (16 slots), slot ^= hd&15
    #pragma unroll
    for (int mf=0;mf<8;mf++)
      #pragma unroll
      for (int cb=0;cb<4;cb++) {
        bf16x4 pk = { (__bf16)acc[mf][cb][0], (__bf16)acc[mf][cb][1],
                      (__bf16)acc[mf][cb][2], (__bf16)acc[mf][cb][3] };
        int hd = cb*16 + lrow;
        int slotv = (mf*2 + (lg>>1)) ^ (hd&15);
        *(bf16x4*)((char*)ws + hd*256 + slotv*16 + (lg&1)*8) = pk;
      }
    #pragma unroll
    for (int p=0;p<16;p++) {
      int idx = p*64 + lane;
      int hd = idx>>4, c = idx&15;
      bf16x8 v = *(const bf16x8*)((char*)ws + hd*256 + ((c ^ (hd&15)))*16);
      *(bf16x8*)(vt + ((size_t)(b*NH + h)*NHD + hd)*NS + s0 + c*8) = v;
    }
  }
}

// ---------------- output projection GEMM: 256x128, BK=64, 3-buffer depth-2 (frozen) ----------------
__global__ __launch_bounds__(512, 2) void k_gemm_out(
    const __bf16* __restrict__ A, const __bf16* __restrict__ Bt,
    const float* __restrict__ bo, float* __restrict__ out) {
  constexpr int BUFE = (256+128)*64;
  __shared__ __align__(16) __bf16 lds[3*BUFE];       // 144 KiB
  const int tid = threadIdx.x;
  const int wid = tid>>6, lane = tid&63;
  const int wr = wid>>1, wc = wid&1;
  const int lrow = lane&15, lg = lane>>4;
  const int srow = lane>>3;
  const int scol = ((lane&7) ^ srow)*8;

  const int id  = blockIdx.x;                        // 256 blocks
  const int xcd = id & 7;
  const int nl  = id >> 3;                           // 0..31
  const int bx  = xcd*4 + (nl >> 3);                 // 0..31
  const int by  = nl & 7;                            // 0..7
  const int m0 = bx*256, n0 = by*128;

  auto stage = [&](int t, int bsel) {
    __bf16* buf = lds + bsel*BUFE;
    const int k0 = t*64;
    #pragma unroll
    for (int i=0;i<4;i++) {
      int c = wid + i*8;
      gload_lds16(A + (size_t)(m0 + c*8 + srow)*ND + k0 + scol, buf + c*512);
    }
    #pragma unroll
    for (int i=0;i<2;i++) {
      int c = wid + i*8;
      gload_lds16(Bt + (size_t)(n0 + c*8 + srow)*ND + k0 + scol, buf + 16384 + c*512);
    }
  };

  int kx[8];
  #pragma unroll
  for (int kk=0;kk<8;kk++) kx[kk] = ((kk ^ (lrow&7)) << 4);
  const int abase = (wr*64 + lrow)*128;
  const int bbase = 32768 + (wc*64 + lrow)*128;

  f32x4 acc[4][4];
  f32x4 zero = {0.f,0.f,0.f,0.f};
  #pragma unroll
  for (int i=0;i<4;i++) for (int j=0;j<4;j++) acc[i][j] = zero;

  stage(0,0);
  stage(1,1);
  for (int t=0; t<16; ++t) {
    if (t < 14) stage(t+2, (t+2)%3);
    if (t < 14)      { VMCNT(12); }
    else if (t == 14){ VMCNT(6);  }
    else             { VMCNT(0);  }
    SBAR();
    const char* L = (const char*)(lds + (t%3)*BUFE);
    bf16x8 bfr[4][2], af[4][2];
    #pragma unroll
    for (int cb=0;cb<4;cb++)
      #pragma unroll
      for (int ksi=0;ksi<2;ksi++)
        bfr[cb][ksi] = *(const bf16x8*)(L + bbase + cb*2048 + kx[ksi*4+lg]);
    #pragma unroll
    for (int mf=0;mf<2;mf++)
      #pragma unroll
      for (int ksi=0;ksi<2;ksi++)
        af[mf][ksi] = *(const bf16x8*)(L + abase + mf*2048 + kx[ksi*4+lg]);
    SCHEDB();
    #pragma unroll
    for (int mf=2;mf<4;mf++)
      #pragma unroll
      for (int ksi=0;ksi<2;ksi++)
        af[mf][ksi] = *(const bf16x8*)(L + abase + mf*2048 + kx[ksi*4+lg]);
    LGKM(4);
    SCHEDB();
    __builtin_amdgcn_s_setprio(1);
    #pragma unroll
    for (int mf=0;mf<2;mf++)
      #pragma unroll
      for (int cb=0;cb<4;cb++)
        #pragma unroll
        for (int ksi=0;ksi<2;ksi++)
          acc[mf][cb] = MFMA16(af[mf][ksi], bfr[cb][ksi], acc[mf][cb]);
    __builtin_amdgcn_s_setprio(0);
    LGKM(0);
    SCHEDB();
    __builtin_amdgcn_s_setprio(1);
    #pragma unroll
    for (int mf=2;mf<4;mf++)
      #pragma unroll
      for (int cb=0;cb<4;cb++)
        #pragma unroll
        for (int ksi=0;ksi<2;ksi++)
          acc[mf][cb] = MFMA16(af[mf][ksi], bfr[cb][ksi], acc[mf][cb]);
    __builtin_amdgcn_s_setprio(0);
    SBAR();
  }

  // epilogue: bias + f32 store (256B segments per 16-lane group, no RMW)
  #pragma unroll
  for (int cb=0;cb<4;cb++) {
    const int n = n0 + wc*64 + cb*16 + lrow;
    const float bias = bo[n];
    #pragma unroll
    for (int mf=0;mf<4;mf++)
      #pragma unroll
      for (int r=0;r<4;r++) {
        const int m = m0 + wr*64 + mf*16 + lg*4 + r;
        out[(size_t)m*ND + n] = acc[mf][cb][r] + bias;
      }
  }
}

// ---------------- flash attention (causal, swapped-QK^T, packed P, padded sP) ----------------
// q/k [B*H][S][HD] bf16, vt [B*H][HD][S] bf16 -> ctx [B][S][H][HD] bf16  (R10/R11 proven)
__global__ __launch_bounds__(256, 3) void k_attn(
    const __bf16* __restrict__ qs, const __bf16* __restrict__ ks,
    const __bf16* __restrict__ vt, __bf16* __restrict__ ctx) {
  __shared__ __align__(16) __bf16 sK[2][64*64];
  __shared__ __align__(16) __bf16 sV[2][64*64];
  __shared__ __align__(16) __bf16 sP[4][32*72];   // [q][kv], stride 72 (144B = 36 banks)
  const int tid = threadIdx.x, w = tid >> 6, lane = tid & 63;
  const int lrow = lane & 15, lg = lane >> 4;
  const int bh = blockIdx.x;
  const int bq = 15 - blockIdx.y;
  const int nt = 2*bq + 2;
  const size_t base = (size_t)bh * NS * NHD;
  const __bf16* Kg = ks + base;
  const __bf16* Vg = vt + base;   // [hd][s]
  __bf16* sPw = sP[w];

  const int q0w = bq*128 + w*32;
  // Q prescaled by (1/sqrt(HD))*log2(e) so P = exp2(S)
  bf16x8 qf[2][2];
  for (int rb=0;rb<2;rb++)
    for (int kk=0;kk<2;kk++) {
      bf16x8 v = *(const bf16x8*)(qs + base + (size_t)(q0w + rb*16 + lrow)*NHD + kk*32 + lg*8);
      bf16x8 o;
      for (int j=0;j<8;j++) o[j] = (__bf16)((float)v[j] * 0.1803368801f);
      qf[rb][kk] = o;
    }

  int koffB[4][2];
  for (int cb=0;cb<4;cb++) {
    int r = cb*16 + lrow;
    for (int kk=0;kk<2;kk++)
      koffB[cb][kk] = r*128 + (((kk*4 + lg) ^ (r & 7)) << 4);
  }
  const int s_r[2]  = { (w + 0)*8 + (lane>>3), (w + 4)*8 + (lane>>3) };
  const int s_u[2]  = { (lane&7) ^ (s_r[0]&7), (lane&7) ^ (s_r[1]&7) };

  f32x4 zero = {0.f,0.f,0.f,0.f};
  f32x4 oacc[2][4];
  float psum[2] = {0.f, 0.f};
  for (int rb=0;rb<2;rb++) for(int cb=0;cb<4;cb++) oacc[rb][cb]=zero;

  for (int i=0;i<2;i++) {
    gload_lds16(Kg + (size_t)s_r[i]*NHD + s_u[i]*8,              sK[0] + (w + i*4)*512);
    gload_lds16(Vg + (size_t)s_r[i]*NS  + s_u[i]*8,              sV[0] + (w + i*4)*512);
  }
  asm volatile("s_waitcnt vmcnt(0)" ::: "memory");
  __syncthreads();

  int buf = 0;
  for (int t = 0; t < nt; ++t) {
    if (t+1 < nt) {
      const __bf16* Kt = Kg + (size_t)(t+1)*64*NHD;
      for (int i=0;i<2;i++) {
        gload_lds16(Kt + (size_t)s_r[i]*NHD + s_u[i]*8,          sK[buf^1] + (w + i*4)*512);
        gload_lds16(Vg + (size_t)s_r[i]*NS + (t+1)*64 + s_u[i]*8, sV[buf^1] + (w + i*4)*512);
      }
    }
    if (!(t == nt-1 && w < 2)) {     // waves 0,1: last tile fully masked -> skip
      const __bf16* bK = sK[buf];
      const __bf16* bV = sV[buf];
      const bool bdry = (t >= nt-2);
      // S^T = K Q^T: lane owns rows kv=cb*16+lg*4+r, col q=rb*16+lrow
      for (int cb=0;cb<4;cb++) {
        bf16x8 kf0 = *(const bf16x8*)((const char*)bK + koffB[cb][0]);
        bf16x8 kf1 = *(const bf16x8*)((const char*)bK + koffB[cb][1]);
        const int kvb = t*64 + cb*16 + lg*4;
        for (int rb=0;rb<2;rb++) {
          f32x4 s4 = MFMA16(kf0, qf[rb][0], zero);
          s4 = MFMA16(kf1, qf[rb][1], s4);
          const int qg = q0w + rb*16 + lrow;
          float e0 = fexp2(s4[0]), e1 = fexp2(s4[1]);
          float e2 = fexp2(s4[2]), e3 = fexp2(s4[3]);
          if (bdry) {
            if (kvb + 0 > qg) e0 = 0.f;
            if (kvb + 1 > qg) e1 = 0.f;
            if (kvb + 2 > qg) e2 = 0.f;
            if (kvb + 3 > qg) e3 = 0.f;
          }
          psum[rb] += (e0 + e1) + (e2 + e3);
          bf16x4 pk = { (__bf16)e0, (__bf16)e1, (__bf16)e2, (__bf16)e3 };
          *(bf16x4*)(sPw + (rb*16 + lrow)*72 + cb*16 + lg*4) = pk;  // ds_write_b64
        }
      }
      // O += P V  (read rows q=lrow(+16), k=kk*32+lg*8)
      for (int kk=0;kk<2;kk++) {
        bf16x8 pa0 = *(const bf16x8*)(sPw + (lrow)*72      + kk*32 + lg*8);
        bf16x8 pa1 = *(const bf16x8*)(sPw + (16 + lrow)*72 + kk*32 + lg*8);
        for (int cb=0;cb<4;cb++) {
          bf16x8 vb = *(const bf16x8*)((const char*)bV + koffB[cb][kk]);
          oacc[0][cb] = MFMA16(pa0, vb, oacc[0][cb]);
          oacc[1][cb] = MFMA16(pa1, vb, oacc[1][cb]);
        }
      }
    }
    asm volatile("s_waitcnt vmcnt(0)" ::: "memory");
    __syncthreads();
    buf ^= 1;
  }

  // psum[rb]: partial row-sum for q=rb*16+lrow over this lane's kv subset
  float inv[2];
  for (int rb=0;rb<2;rb++) {
    float s = psum[rb];
    s += __shfl_xor(s, 16);
    s += __shfl_xor(s, 32);
    inv[rb] = 1.0f / s;
  }

  // ---- coalesced ctx write via LDS restage (reuse sK; all waves synced) ----
  __bf16* ws = &sK[0][0] + w*2048;            // 32 rows x 64 cols per wave
  const int b = bh >> 4, h = bh & 15;
  for (int rb=0;rb<2;rb++)
    for (int cb=0;cb<4;cb++)
      for (int r=0;r<4;r++) {
        int row = rb*16 + lg*4 + r;
        float nrm = __shfl(inv[rb], lg*4 + r);
        int chunk = (cb*2 + (lrow>>3)) ^ (row&7);
        *(__bf16*)((char*)ws + row*128 + chunk*16 + (lrow&7)*2) =
            (__bf16)(oacc[rb][cb][r] * nrm);
      }
  for (int p=0;p<4;p++) {
    int row = p*8 + (lane>>3);
    int chunk = (lane&7) ^ (row&7);
    bf16x8 v = *(const bf16x8*)((char*)ws + row*128 + chunk*16);
    int q = q0w + row;
    *(bf16x8*)(ctx + ((size_t)(b*NS + q))*ND + h*NHD + (lane&7)*8) = v;
  }
}

extern "C" void kernel_launch(void* const* d_in, const int* in_sizes, int n_in,
                              void* d_out, int out_size, void* d_ws, size_t ws_size,
                              hipStream_t stream) {
  const float* x  = (const float*)d_in[0];
  const float* Wq = (const float*)d_in[1];
  const float* Wk = (const float*)d_in[2];
  const float* Wv = (const float*)d_in[3];
  const float* Wo = (const float*)d_in[4];
  const float* bo = (const float*)d_in[5];
  float* out = (float*)d_out;

  __bf16* xb    = (__bf16*)d_ws;
  __bf16* wqkvt = xb    + (size_t)NTOK*ND;
  __bf16* wot   = wqkvt + (size_t)3*ND*ND;
  __bf16* qsc   = wot   + (size_t)ND*ND;
  __bf16* ksc   = qsc   + (size_t)NTOK*ND;
  __bf16* vtc   = ksc   + (size_t)NTOK*ND;
  __bf16* ctx   = vtc   + (size_t)NTOK*ND;

  k_prep<<<1024 + NTOK*ND/(4*256), 256, 0, stream>>>(x, Wq, Wk, Wv, Wo, xb, wqkvt, wot);
  k_gemm_qkv<<<768, 256, 0, stream>>>(xb, wqkvt, qsc, ksc, vtc);
  k_attn<<<dim3(NB*NH, NS/128), 256, 0, stream>>>(qsc, ksc, vtc, ctx);
  k_gemm_out<<<256, 512, 0, stream>>>(ctx, wot, bo, out);
}